// Round 14
// baseline (303.973 us; speedup 1.0000x reference)
//
#include <hip/hip_runtime.h>
#include <hip/hip_fp16.h>

#define HID 64
#define NF 5
#define NC 5

#define WSH 9                 // window shift: 512 nodes per window
#define WINN 512              // nodes per window (== blockDim of k_csr)
#define NBMAX 256             // max windows (N <= 131072)
#define SRCB 17               // bits for src in packed pair (N <= 131072); dstLocal 9 bits
#define NBLK 256              // blocks for bcount/bfill (measured-best)

// ---------------- bucketed CSR build ----------------

// Pass 1: per-(block,bucket) histogram -> cntmat[blk][bucket] (coalesced store).
__global__ __launch_bounds__(512) void k_bcount(const int* __restrict__ dst, int E, int chunk,
                                                int nb, int* __restrict__ cntmat) {
    __shared__ int cnt[NBMAX];
    int t = threadIdx.x;
    for (int i = t; i < nb; i += 512) cnt[i] = 0;
    __syncthreads();
    int c0 = blockIdx.x * chunk;
    int c1 = c0 + chunk; if (c1 > E) c1 = E;
    for (int i = c0 + t * 4; i < c1; i += 512 * 4) {
        if (i + 3 < c1) {
            int4 d4 = *reinterpret_cast<const int4*>(dst + i);
            atomicAdd(&cnt[d4.x >> WSH], 1);
            atomicAdd(&cnt[d4.y >> WSH], 1);
            atomicAdd(&cnt[d4.z >> WSH], 1);
            atomicAdd(&cnt[d4.w >> WSH], 1);
        } else {
            for (int k = i; k < c1; ++k) atomicAdd(&cnt[dst[k] >> WSH], 1);
        }
    }
    __syncthreads();
    for (int i = t; i < nb; i += 512) cntmat[blockIdx.x * nb + i] = cnt[i];
}

// Pass 2a: per-bucket exclusive scan over the NBLK block counts (in place) + btot.
__global__ __launch_bounds__(NBLK) void k_wscan(int* __restrict__ cntmat, int nb,
                                                int* __restrict__ btot) {
    __shared__ int s[NBLK];
    int b = blockIdx.x;       // bucket
    int t = threadIdx.x;      // block index
    int v = cntmat[t * nb + b];
    s[t] = v;
    __syncthreads();
    for (int o = 1; o < NBLK; o <<= 1) {
        int u = (t >= o) ? s[t - o] : 0;
        __syncthreads();
        s[t] += u;
        __syncthreads();
    }
    cntmat[t * nb + b] = s[t] - v;            // exclusive prefix within bucket
    if (t == NBLK - 1) btot[b] = s[t];
}

// Pass 2b: exclusive scan of bucket totals -> bbase; offsets[N] = E.
__global__ __launch_bounds__(256) void k_bscan2(const int* __restrict__ btot, int nb, int N,
                                                int* __restrict__ bbase,
                                                int* __restrict__ offsets) {
    __shared__ int s[256];
    int t = threadIdx.x;
    int v = (t < nb) ? btot[t] : 0;
    s[t] = v;
    __syncthreads();
    for (int o = 1; o < 256; o <<= 1) {
        int u = (t >= o) ? s[t - o] : 0;
        __syncthreads();
        s[t] += u;
        __syncthreads();
    }
    if (t < nb) bbase[t] = s[t] - v;
    if (t == nb - 1) { bbase[nb] = s[t]; offsets[N] = s[t]; }
}

// Pass 3: scatter-only fill (bases precomputed); int4-vectorized src/dst reads.
__global__ __launch_bounds__(512) void k_bfill(const int* __restrict__ src,
                                               const int* __restrict__ dst, int E, int chunk,
                                               int nb, const int* __restrict__ bbase,
                                               const int* __restrict__ cntmat,
                                               unsigned int* __restrict__ pairbuf) {
    __shared__ int wcur[NBMAX];
    int t = threadIdx.x;
    int blk = blockIdx.x;
    for (int i = t; i < nb; i += 512)
        wcur[i] = bbase[i] + cntmat[blk * nb + i];
    __syncthreads();
    int c0 = blk * chunk;
    int c1 = c0 + chunk; if (c1 > E) c1 = E;
    for (int i = c0 + t * 4; i < c1; i += 512 * 4) {
        if (i + 3 < c1) {
            int4 d4 = *reinterpret_cast<const int4*>(dst + i);
            int4 s4 = *reinterpret_cast<const int4*>(src + i);
            int p;
            p = atomicAdd(&wcur[d4.x >> WSH], 1);
            pairbuf[p] = ((unsigned)(d4.x & (WINN - 1)) << SRCB) | (unsigned)s4.x;
            p = atomicAdd(&wcur[d4.y >> WSH], 1);
            pairbuf[p] = ((unsigned)(d4.y & (WINN - 1)) << SRCB) | (unsigned)s4.y;
            p = atomicAdd(&wcur[d4.z >> WSH], 1);
            pairbuf[p] = ((unsigned)(d4.z & (WINN - 1)) << SRCB) | (unsigned)s4.z;
            p = atomicAdd(&wcur[d4.w >> WSH], 1);
            pairbuf[p] = ((unsigned)(d4.w & (WINN - 1)) << SRCB) | (unsigned)s4.w;
        } else {
            for (int k = i; k < c1; ++k) {
                int d = dst[k];
                int p = atomicAdd(&wcur[d >> WSH], 1);
                pairbuf[p] = ((unsigned)(d & (WINN - 1)) << SRCB) | (unsigned)src[k];
            }
        }
    }
}

// Pass 4: one block per 512-node window. Exclusive ownership of pair/CSR region.
// Emits offsets, csr_src, dinv, and xs8[n] = {x[n,3,:]*dinv[n], pad 0} (32 B rows).
// Scan: per-wave shfl_up + 8-entry cross-wave fixup.
__global__ __launch_bounds__(WINN) void k_csr(const unsigned int* __restrict__ pairbuf,
                                              const int* __restrict__ bbase, int N,
                                              const float* __restrict__ x,
                                              int* __restrict__ offsets,
                                              int* __restrict__ csr_src,
                                              float* __restrict__ dinv,
                                              float* __restrict__ xs8) {
    int b = blockIdx.x, t = threadIdx.x;
    int lane = t & 63, w = t >> 6;
    int winStart = b << WSH;
    int rbeg = bbase[b], rend = bbase[b + 1];
    __shared__ int deg[WINN];
    __shared__ int cur[WINN];
    __shared__ int wsum[8];
    deg[t] = 0;
    __syncthreads();
    for (int p = rbeg + t; p < rend; p += WINN)
        atomicAdd(&deg[pairbuf[p] >> SRCB], 1);
    __syncthreads();
    int v = deg[t];
    int inc = v;
#pragma unroll
    for (int o = 1; o < 64; o <<= 1) {
        int u = __shfl_up(inc, o, 64);
        if (lane >= o) inc += u;
    }
    if (lane == 63) wsum[w] = inc;
    __syncthreads();
    int wbase = 0;
#pragma unroll
    for (int i = 0; i < 8; ++i) wbase += (i < w) ? wsum[i] : 0;
    int excl = wbase + inc - v;               // exclusive prefix over block
    int node = winStart + t;
    if (node < N) {
        int base = rbeg + excl;
        offsets[node] = base;
        cur[t] = base;
        float dv = rsqrtf((float)v + 1.0f);
        dinv[node] = dv;
        const float* xr = x + (size_t)node * (4 * NF) + 3 * NF;
        float4 v0, v1;
        v0.x = xr[0] * dv; v0.y = xr[1] * dv; v0.z = xr[2] * dv; v0.w = xr[3] * dv;
        v1.x = xr[4] * dv; v1.y = 0.f; v1.z = 0.f; v1.w = 0.f;
        float4* xp = reinterpret_cast<float4*>(xs8 + (size_t)node * 8);
        xp[0] = v0;
        xp[1] = v1;
    }
    __syncthreads();
    for (int p = rbeg + t; p < rend; p += WINN) {
        unsigned u = pairbuf[p];
        int dl = u >> SRCB;
        int sn = u & ((1u << SRCB) - 1);
        int pos = atomicAdd(&cur[dl], 1);
        csr_src[pos] = sn;
    }
}

// ---------------- GCN layers ----------------

// Layer-1, aggregation in padded 8-float input space; g1 stored as fp16.
// g1[d] = relu( dinv[d]*(xs[d] + Σ_s xs[s]) @ W1 + b1 ) * dinv[d]
__global__ __launch_bounds__(256) void k_aggX(const float* __restrict__ xs8,
                                              const float* __restrict__ W1,
                                              const int* __restrict__ offsets,
                                              const int* __restrict__ csr_src,
                                              const float* __restrict__ dinv,
                                              const float* __restrict__ b1,
                                              __half* __restrict__ g1, int N) {
    int wid = (blockIdx.x * blockDim.x + threadIdx.x) >> 6;
    int lane = threadIdx.x & 63;
    int g = lane >> 1;              // 32 edge groups
    int h = lane & 1;               // half-row selector (features h*4..h*4+3)
    float w0 = W1[0 * HID + lane], w1 = W1[1 * HID + lane], w2 = W1[2 * HID + lane],
          w3 = W1[3 * HID + lane], w4 = W1[4 * HID + lane];
    if (wid >= N) return;
    int e0 = offsets[wid], e1 = offsets[wid + 1];
    float4 acc = {0.f, 0.f, 0.f, 0.f};
    int ee = e0 + g;
    int s = (ee < e1) ? csr_src[ee] : -1;
    for (int e = e0; e < e1; e += 32) {
        int cs = s;
        int en = e + 32 + g;
        s = (en < e1) ? csr_src[en] : -1;       // prefetch next iter's index
        bool p = (cs >= 0);
        int csc = p ? cs : 0;                   // clamp: load always (exec-unmasked)
        float4 v = *reinterpret_cast<const float4*>(xs8 + (size_t)csc * 8 + (h << 2));
        if (p) { acc.x += v.x; acc.y += v.y; acc.z += v.z; acc.w += v.w; }
    }
    if (g == 0) {                               // self term (lanes 0,1)
        float4 v = *reinterpret_cast<const float4*>(xs8 + (size_t)wid * 8 + (h << 2));
        acc.x += v.x; acc.y += v.y; acc.z += v.z; acc.w += v.w;
    }
#pragma unroll
    for (int o = 2; o < 64; o <<= 1) {
        acc.x += __shfl_xor(acc.x, o, 64);
        acc.y += __shfl_xor(acc.y, o, 64);
        acc.z += __shfl_xor(acc.z, o, 64);
        acc.w += __shfl_xor(acc.w, o, 64);
    }
    float a0 = __shfl(acc.x, 0, 2), a1 = __shfl(acc.y, 0, 2),
          a2 = __shfl(acc.z, 0, 2), a3 = __shfl(acc.w, 0, 2),
          a4 = __shfl(acc.x, 1, 2);
    float dv = dinv[wid];
    float sres = a0 * w0 + a1 * w1 + a2 * w2 + a3 * w3 + a4 * w4;
    float r = fmaxf(fmaf(dv, sres, b1[lane]), 0.f) * dv;  // g1 = relu(.)*dinv
    g1[(size_t)wid * HID + lane] = __float2half(r);
}

// Merged layer-2 aggregate + MLP tail. Per block: 32 nodes (4 waves x 8 nodes),
// W2/Wout staged once in LDS. Per node:
//   row = dinv*(g1[d] + Σ g1[s])   (gather, 32 rows in flight, xor-reduce)
//   h2[lane] = relu(row @ W2[:,lane] + b2[lane])      (shfl-broadcast + LDS W2)
//   logits = h2 @ Wout + bout -> softmax -> out       (butterfly reduce)
__global__ __launch_bounds__(256) void k_aggF(const __half* __restrict__ g1,
                                              const int* __restrict__ offsets,
                                              const int* __restrict__ csr_src,
                                              const float* __restrict__ dinv,
                                              const float* __restrict__ W2,
                                              const float* __restrict__ b2,
                                              const float* __restrict__ Wout,
                                              const float* __restrict__ bout,
                                              float* __restrict__ out, int N) {
    __shared__ float sW2[HID * HID];      // 16 KB, sW2[k*64+f]
    __shared__ float swout[HID * NC];
    __shared__ float sb2[HID];
    __shared__ float sbout[8];
    int tx = threadIdx.x;
    const float4* W2_4 = reinterpret_cast<const float4*>(W2);
    float4* sW2_4 = reinterpret_cast<float4*>(sW2);
    for (int i = tx; i < HID * 16; i += 256) sW2_4[i] = W2_4[i];
    for (int i = tx; i < HID * NC; i += 256) swout[i] = Wout[i];
    if (tx < HID) sb2[tx] = b2[tx];
    if (tx < NC) sbout[tx] = bout[tx];
    __syncthreads();

    int w = tx >> 6, lane = tx & 63;
    int g = lane >> 3;              // 8 edge groups
    int f8 = (lane & 7) << 3;       // 8 features per lane
    int nodeBase = blockIdx.x * 32 + w * 8;

    for (int j = 0; j < 8; ++j) {
        int wid = nodeBase + j;
        if (wid >= N) break;
        int e0 = offsets[wid], e1 = offsets[wid + 1];
        float acc[8];
#pragma unroll
        for (int i = 0; i < 8; ++i) acc[i] = 0.f;
        int ee = e0 + g;
        int s0 = (ee < e1) ? csr_src[ee] : -1;
        int s1 = (ee + 8 < e1) ? csr_src[ee + 8] : -1;
        int s2 = (ee + 16 < e1) ? csr_src[ee + 16] : -1;
        int s3 = (ee + 24 < e1) ? csr_src[ee + 24] : -1;
        for (int e = e0; e < e1; e += 32) {
            int cs0 = s0, cs1 = s1, cs2 = s2, cs3 = s3;
            int nx = e + 32 + g;
            s0 = (nx < e1) ? csr_src[nx] : -1;
            s1 = (nx + 8 < e1) ? csr_src[nx + 8] : -1;
            s2 = (nx + 16 < e1) ? csr_src[nx + 16] : -1;
            s3 = (nx + 24 < e1) ? csr_src[nx + 24] : -1;
            bool p0 = (cs0 >= 0), p1 = (cs1 >= 0), p2 = (cs2 >= 0), p3 = (cs3 >= 0);
            int c0 = p0 ? cs0 : 0, c1 = p1 ? cs1 : 0, c2 = p2 ? cs2 : 0, c3 = p3 ? cs3 : 0;
            float4 raw0 = *reinterpret_cast<const float4*>(g1 + (size_t)c0 * HID + f8);
            float4 raw1 = *reinterpret_cast<const float4*>(g1 + (size_t)c1 * HID + f8);
            float4 raw2 = *reinterpret_cast<const float4*>(g1 + (size_t)c2 * HID + f8);
            float4 raw3 = *reinterpret_cast<const float4*>(g1 + (size_t)c3 * HID + f8);
            if (p0) {
                float2 q0 = __half22float2(*reinterpret_cast<__half2*>(&raw0.x));
                float2 q1 = __half22float2(*reinterpret_cast<__half2*>(&raw0.y));
                float2 q2 = __half22float2(*reinterpret_cast<__half2*>(&raw0.z));
                float2 q3 = __half22float2(*reinterpret_cast<__half2*>(&raw0.w));
                acc[0] += q0.x; acc[1] += q0.y; acc[2] += q1.x; acc[3] += q1.y;
                acc[4] += q2.x; acc[5] += q2.y; acc[6] += q3.x; acc[7] += q3.y;
            }
            if (p1) {
                float2 q0 = __half22float2(*reinterpret_cast<__half2*>(&raw1.x));
                float2 q1 = __half22float2(*reinterpret_cast<__half2*>(&raw1.y));
                float2 q2 = __half22float2(*reinterpret_cast<__half2*>(&raw1.z));
                float2 q3 = __half22float2(*reinterpret_cast<__half2*>(&raw1.w));
                acc[0] += q0.x; acc[1] += q0.y; acc[2] += q1.x; acc[3] += q1.y;
                acc[4] += q2.x; acc[5] += q2.y; acc[6] += q3.x; acc[7] += q3.y;
            }
            if (p2) {
                float2 q0 = __half22float2(*reinterpret_cast<__half2*>(&raw2.x));
                float2 q1 = __half22float2(*reinterpret_cast<__half2*>(&raw2.y));
                float2 q2 = __half22float2(*reinterpret_cast<__half2*>(&raw2.z));
                float2 q3 = __half22float2(*reinterpret_cast<__half2*>(&raw2.w));
                acc[0] += q0.x; acc[1] += q0.y; acc[2] += q1.x; acc[3] += q1.y;
                acc[4] += q2.x; acc[5] += q2.y; acc[6] += q3.x; acc[7] += q3.y;
            }
            if (p3) {
                float2 q0 = __half22float2(*reinterpret_cast<__half2*>(&raw3.x));
                float2 q1 = __half22float2(*reinterpret_cast<__half2*>(&raw3.y));
                float2 q2 = __half22float2(*reinterpret_cast<__half2*>(&raw3.z));
                float2 q3 = __half22float2(*reinterpret_cast<__half2*>(&raw3.w));
                acc[0] += q0.x; acc[1] += q0.y; acc[2] += q1.x; acc[3] += q1.y;
                acc[4] += q2.x; acc[5] += q2.y; acc[6] += q3.x; acc[7] += q3.y;
            }
        }
        // butterfly over the 8 edge groups: every lane ends with the full sum for
        // its 8 features (f8..f8+7)
#pragma unroll
        for (int o = 8; o < 64; o <<= 1) {
#pragma unroll
            for (int i = 0; i < 8; ++i) acc[i] += __shfl_xor(acc[i], o, 64);
        }
        // self term + dinv scale -> row (all lanes)
        float4 raw = *reinterpret_cast<const float4*>(g1 + (size_t)wid * HID + f8);
        float2 q0 = __half22float2(*reinterpret_cast<__half2*>(&raw.x));
        float2 q1 = __half22float2(*reinterpret_cast<__half2*>(&raw.y));
        float2 q2 = __half22float2(*reinterpret_cast<__half2*>(&raw.z));
        float2 q3 = __half22float2(*reinterpret_cast<__half2*>(&raw.w));
        float dv = dinv[wid];
        float row[8];
        row[0] = dv * (acc[0] + q0.x); row[1] = dv * (acc[1] + q0.y);
        row[2] = dv * (acc[2] + q1.x); row[3] = dv * (acc[3] + q1.y);
        row[4] = dv * (acc[4] + q2.x); row[5] = dv * (acc[5] + q2.y);
        row[6] = dv * (acc[6] + q3.x); row[7] = dv * (acc[7] + q3.y);
        // h2[lane] = relu( row @ W2[:,lane] + b2[lane] )
        float h2 = sb2[lane];
#pragma unroll
        for (int c = 0; c < 8; ++c) {
#pragma unroll
            for (int i = 0; i < 8; ++i) {
                float rk = __shfl(row[i], c, 8);     // row value of feature c*8+i
                h2 = fmaf(rk, sW2[(c * 8 + i) * HID + lane], h2);
            }
        }
        h2 = fmaxf(h2, 0.f);
        // logits: reduce h2 * Wout[lane][c] over 64 lanes
        float pl[NC];
#pragma unroll
        for (int c = 0; c < NC; ++c) pl[c] = h2 * swout[lane * NC + c];
#pragma unroll
        for (int o = 1; o < 64; o <<= 1) {
#pragma unroll
            for (int c = 0; c < NC; ++c) pl[c] += __shfl_xor(pl[c], o, 64);
        }
        if (lane < NC) {
            float lg[NC];
#pragma unroll
            for (int c = 0; c < NC; ++c) lg[c] = pl[c] + sbout[c];
            float m = lg[0];
#pragma unroll
            for (int c = 1; c < NC; ++c) m = fmaxf(m, lg[c]);
            float ssum = 0.f, ex[NC];
#pragma unroll
            for (int c = 0; c < NC; ++c) { ex[c] = __expf(lg[c] - m); ssum += ex[c]; }
            out[(size_t)wid * NC + lane] = ex[lane] / ssum;
        }
    }
}

// ---------------- launch ----------------

extern "C" void kernel_launch(void* const* d_in, const int* in_sizes, int n_in,
                              void* d_out, int out_size, void* d_ws, size_t ws_size,
                              hipStream_t stream) {
    const float* x   = (const float*)d_in[0];
    const int*   ei  = (const int*)d_in[1];     // [2, E]: src = ei, dst = ei+E
    const float* W1  = (const float*)d_in[3];
    const float* b1  = (const float*)d_in[4];
    const float* W2  = (const float*)d_in[5];
    const float* b2  = (const float*)d_in[6];
    const float* Wo  = (const float*)d_in[7];
    const float* bo  = (const float*)d_in[8];
    float* out = (float*)d_out;

    const int N = in_sizes[2];          // batch array length = N_NODES (assumed <= 131072)
    const int E = in_sizes[1] / 2;

    // workspace partition (256B aligned)
    size_t off = 0;
    char* base = (char*)d_ws;
    auto alloc = [&](size_t bytes) -> void* {
        off = (off + 255) & ~(size_t)255;
        void* r = base + off;
        off += bytes;
        return r;
    };
    int*      cntmat  = (int*)alloc((size_t)NBLK * NBMAX * 4);
    int*      btot    = (int*)alloc((size_t)NBMAX * 4);
    int*      bbase   = (int*)alloc(((size_t)NBMAX + 1) * 4);
    unsigned* pairbuf = (unsigned*)alloc((size_t)E * 4);
    int*      offsets = (int*)alloc(((size_t)N + 1) * 4);
    int*      csr_src = (int*)alloc((size_t)E * 4);
    float*    dinv    = (float*)alloc((size_t)N * 4);
    float*    xs8     = (float*)alloc((size_t)N * 8 * 4);
    __half*   g1      = (__half*)alloc((size_t)N * HID * 2);

    const int T = 256;
    int gNF = ((N * HID) + T - 1) / T;    // one wave per node (4 waves/block)

    const int* src = ei;
    const int* dst = ei + E;

    int nb = (N + WINN - 1) >> WSH;                      // number of windows/buckets (<= 256)
    int chunk = (((E + NBLK - 1) / NBLK) + 3) & ~3;      // edges per fill block, multiple of 4

    // bucketed CSR build (+ xs8 table)
    k_bcount<<<NBLK, 512, 0, stream>>>(dst, E, chunk, nb, cntmat);
    k_wscan<<<nb, NBLK, 0, stream>>>(cntmat, nb, btot);
    k_bscan2<<<1, 256, 0, stream>>>(btot, nb, N, bbase, offsets);
    k_bfill<<<NBLK, 512, 0, stream>>>(src, dst, E, chunk, nb, bbase, cntmat, pairbuf);
    k_csr<<<nb, WINN, 0, stream>>>(pairbuf, bbase, N, x, offsets, csr_src, dinv, xs8);

    // layer 1: aggregate xs8 in input space, then @W1 per node: g1 = relu(.)*dinv (fp16)
    k_aggX<<<gNF, T, 0, stream>>>(xs8, W1, offsets, csr_src, dinv, b1, g1, N);

    // merged layer-2 aggregate + W2 + Wout + softmax (32 nodes per block)
    int gF = (N + 31) / 32;
    k_aggF<<<gF, 256, 0, stream>>>(g1, offsets, csr_src, dinv, W2, b2, Wo, bo, out, N);
}

// Round 16
// 200.641 us; speedup vs baseline: 1.5150x; 1.5150x over previous
//
#include <hip/hip_runtime.h>
#include <hip/hip_fp16.h>

#define HID 64
#define NF 5
#define NC 5

#define WSH 9                 // window shift: 512 nodes per window
#define WINN 512              // nodes per window (== blockDim of k_csr)
#define NBMAX 256             // max windows (N <= 131072)
#define SRCB 17               // bits for src in packed pair (N <= 131072); dstLocal 9 bits
#define NBLK 256              // blocks for bcount/bfill (measured-best)

// ---------------- bucketed CSR build ----------------

// Pass 1: per-(block,bucket) histogram -> cntmat[blk][bucket] (coalesced store).
// int4-vectorized dst reads (chunk is a multiple of 4; dst base 16B-aligned).
__global__ __launch_bounds__(512) void k_bcount(const int* __restrict__ dst, int E, int chunk,
                                                int nb, int* __restrict__ cntmat) {
    __shared__ int cnt[NBMAX];
    int t = threadIdx.x;
    for (int i = t; i < nb; i += 512) cnt[i] = 0;
    __syncthreads();
    int c0 = blockIdx.x * chunk;
    int c1 = c0 + chunk; if (c1 > E) c1 = E;
    for (int i = c0 + t * 4; i < c1; i += 512 * 4) {
        if (i + 3 < c1) {
            int4 d4 = *reinterpret_cast<const int4*>(dst + i);
            atomicAdd(&cnt[d4.x >> WSH], 1);
            atomicAdd(&cnt[d4.y >> WSH], 1);
            atomicAdd(&cnt[d4.z >> WSH], 1);
            atomicAdd(&cnt[d4.w >> WSH], 1);
        } else {
            for (int k = i; k < c1; ++k) atomicAdd(&cnt[dst[k] >> WSH], 1);
        }
    }
    __syncthreads();
    for (int i = t; i < nb; i += 512) cntmat[blockIdx.x * nb + i] = cnt[i];
}

// Pass 2a: per-bucket exclusive scan over the NBLK block counts (in place) + btot.
__global__ __launch_bounds__(NBLK) void k_wscan(int* __restrict__ cntmat, int nb,
                                                int* __restrict__ btot) {
    __shared__ int s[NBLK];
    int b = blockIdx.x;       // bucket
    int t = threadIdx.x;      // block index
    int v = cntmat[t * nb + b];
    s[t] = v;
    __syncthreads();
    for (int o = 1; o < NBLK; o <<= 1) {
        int u = (t >= o) ? s[t - o] : 0;
        __syncthreads();
        s[t] += u;
        __syncthreads();
    }
    cntmat[t * nb + b] = s[t] - v;            // exclusive prefix within bucket
    if (t == NBLK - 1) btot[b] = s[t];
}

// Pass 2b: exclusive scan of bucket totals -> bbase; offsets[N] = E.
__global__ __launch_bounds__(256) void k_bscan2(const int* __restrict__ btot, int nb, int N,
                                                int* __restrict__ bbase,
                                                int* __restrict__ offsets) {
    __shared__ int s[256];
    int t = threadIdx.x;
    int v = (t < nb) ? btot[t] : 0;
    s[t] = v;
    __syncthreads();
    for (int o = 1; o < 256; o <<= 1) {
        int u = (t >= o) ? s[t - o] : 0;
        __syncthreads();
        s[t] += u;
        __syncthreads();
    }
    if (t < nb) bbase[t] = s[t] - v;
    if (t == nb - 1) { bbase[nb] = s[t]; offsets[N] = s[t]; }
}

// Pass 3: scatter-only fill (bases precomputed); int4-vectorized src/dst reads.
__global__ __launch_bounds__(512) void k_bfill(const int* __restrict__ src,
                                               const int* __restrict__ dst, int E, int chunk,
                                               int nb, const int* __restrict__ bbase,
                                               const int* __restrict__ cntmat,
                                               unsigned int* __restrict__ pairbuf) {
    __shared__ int wcur[NBMAX];
    int t = threadIdx.x;
    int blk = blockIdx.x;
    for (int i = t; i < nb; i += 512)
        wcur[i] = bbase[i] + cntmat[blk * nb + i];
    __syncthreads();
    int c0 = blk * chunk;
    int c1 = c0 + chunk; if (c1 > E) c1 = E;
    for (int i = c0 + t * 4; i < c1; i += 512 * 4) {
        if (i + 3 < c1) {
            int4 d4 = *reinterpret_cast<const int4*>(dst + i);
            int4 s4 = *reinterpret_cast<const int4*>(src + i);
            int p;
            p = atomicAdd(&wcur[d4.x >> WSH], 1);
            pairbuf[p] = ((unsigned)(d4.x & (WINN - 1)) << SRCB) | (unsigned)s4.x;
            p = atomicAdd(&wcur[d4.y >> WSH], 1);
            pairbuf[p] = ((unsigned)(d4.y & (WINN - 1)) << SRCB) | (unsigned)s4.y;
            p = atomicAdd(&wcur[d4.z >> WSH], 1);
            pairbuf[p] = ((unsigned)(d4.z & (WINN - 1)) << SRCB) | (unsigned)s4.z;
            p = atomicAdd(&wcur[d4.w >> WSH], 1);
            pairbuf[p] = ((unsigned)(d4.w & (WINN - 1)) << SRCB) | (unsigned)s4.w;
        } else {
            for (int k = i; k < c1; ++k) {
                int d = dst[k];
                int p = atomicAdd(&wcur[d >> WSH], 1);
                pairbuf[p] = ((unsigned)(d & (WINN - 1)) << SRCB) | (unsigned)src[k];
            }
        }
    }
}

// Pass 4: one block per 512-node window. Exclusive ownership of pair/CSR region.
// Emits offsets, csr_src, dinv, and xs8[n] = {x[n,3,:]*dinv[n], pad 0} (32 B rows).
// Scan: per-wave shfl_up + 8-entry cross-wave fixup.
__global__ __launch_bounds__(WINN) void k_csr(const unsigned int* __restrict__ pairbuf,
                                              const int* __restrict__ bbase, int N,
                                              const float* __restrict__ x,
                                              int* __restrict__ offsets,
                                              int* __restrict__ csr_src,
                                              float* __restrict__ dinv,
                                              float* __restrict__ xs8) {
    int b = blockIdx.x, t = threadIdx.x;
    int lane = t & 63, w = t >> 6;
    int winStart = b << WSH;
    int rbeg = bbase[b], rend = bbase[b + 1];
    __shared__ int deg[WINN];
    __shared__ int cur[WINN];
    __shared__ int wsum[8];
    deg[t] = 0;
    __syncthreads();
    for (int p = rbeg + t; p < rend; p += WINN)
        atomicAdd(&deg[pairbuf[p] >> SRCB], 1);
    __syncthreads();
    int v = deg[t];
    int inc = v;
#pragma unroll
    for (int o = 1; o < 64; o <<= 1) {
        int u = __shfl_up(inc, o, 64);
        if (lane >= o) inc += u;
    }
    if (lane == 63) wsum[w] = inc;
    __syncthreads();
    int wbase = 0;
#pragma unroll
    for (int i = 0; i < 8; ++i) wbase += (i < w) ? wsum[i] : 0;
    int excl = wbase + inc - v;               // exclusive prefix over block
    int node = winStart + t;
    if (node < N) {
        int base = rbeg + excl;
        offsets[node] = base;
        cur[t] = base;
        float dv = rsqrtf((float)v + 1.0f);
        dinv[node] = dv;
        const float* xr = x + (size_t)node * (4 * NF) + 3 * NF;
        float4 v0, v1;
        v0.x = xr[0] * dv; v0.y = xr[1] * dv; v0.z = xr[2] * dv; v0.w = xr[3] * dv;
        v1.x = xr[4] * dv; v1.y = 0.f; v1.z = 0.f; v1.w = 0.f;
        float4* xp = reinterpret_cast<float4*>(xs8 + (size_t)node * 8);
        xp[0] = v0;
        xp[1] = v1;
    }
    __syncthreads();
    for (int p = rbeg + t; p < rend; p += WINN) {
        unsigned u = pairbuf[p];
        int dl = u >> SRCB;
        int sn = u & ((1u << SRCB) - 1);
        int pos = atomicAdd(&cur[dl], 1);
        csr_src[pos] = sn;
    }
}

// ---------------- GCN layers ----------------

// Layer-1, aggregation in padded 8-float input space; g1 stored as fp16.
// g1[d] = relu( dinv[d]*(xs[d] + Σ_s xs[s]) @ W1 + b1 ) * dinv[d]
// Wave: 32 edge groups (g=lane>>1) x 2 lanes; lane h=lane&1 loads float4 half-row.
__global__ __launch_bounds__(256) void k_aggX(const float* __restrict__ xs8,
                                              const float* __restrict__ W1,
                                              const int* __restrict__ offsets,
                                              const int* __restrict__ csr_src,
                                              const float* __restrict__ dinv,
                                              const float* __restrict__ b1,
                                              __half* __restrict__ g1, int N) {
    int wid = (blockIdx.x * blockDim.x + threadIdx.x) >> 6;
    int lane = threadIdx.x & 63;
    int g = lane >> 1;              // 32 edge groups
    int h = lane & 1;               // half-row selector (features h*4..h*4+3)
    float w0 = W1[0 * HID + lane], w1 = W1[1 * HID + lane], w2 = W1[2 * HID + lane],
          w3 = W1[3 * HID + lane], w4 = W1[4 * HID + lane];
    if (wid >= N) return;
    int e0 = offsets[wid], e1 = offsets[wid + 1];
    float4 acc = {0.f, 0.f, 0.f, 0.f};
    int ee = e0 + g;
    int s = (ee < e1) ? csr_src[ee] : -1;
    for (int e = e0; e < e1; e += 32) {
        int cs = s;
        int en = e + 32 + g;
        s = (en < e1) ? csr_src[en] : -1;       // prefetch next iter's index
        bool p = (cs >= 0);
        int csc = p ? cs : 0;                   // clamp: load always (exec-unmasked)
        float4 v = *reinterpret_cast<const float4*>(xs8 + (size_t)csc * 8 + (h << 2));
        if (p) { acc.x += v.x; acc.y += v.y; acc.z += v.z; acc.w += v.w; }
    }
    if (g == 0) {                               // self term (lanes 0,1)
        float4 v = *reinterpret_cast<const float4*>(xs8 + (size_t)wid * 8 + (h << 2));
        acc.x += v.x; acc.y += v.y; acc.z += v.z; acc.w += v.w;
    }
#pragma unroll
    for (int o = 2; o < 64; o <<= 1) {
        acc.x += __shfl_xor(acc.x, o, 64);
        acc.y += __shfl_xor(acc.y, o, 64);
        acc.z += __shfl_xor(acc.z, o, 64);
        acc.w += __shfl_xor(acc.w, o, 64);
    }
    float a0 = __shfl(acc.x, 0, 2), a1 = __shfl(acc.y, 0, 2),
          a2 = __shfl(acc.z, 0, 2), a3 = __shfl(acc.w, 0, 2),
          a4 = __shfl(acc.x, 1, 2);
    float dv = dinv[wid];
    float sres = a0 * w0 + a1 * w1 + a2 * w2 + a3 * w3 + a4 * w4;
    float r = fmaxf(fmaf(dv, sres, b1[lane]), 0.f) * dv;  // g1 = relu(.)*dinv
    g1[(size_t)wid * HID + lane] = __float2half(r);
}

// Layer-2 pre-matmul aggregate over fp16 g1 rows (128 B each), unroll x4:
// 32 rows in flight per wave. aggH[d] = dinv[d]*( g1[d] + Σ_s g1[s] ), fp16 out.
__global__ __launch_bounds__(256) void k_aggG(const __half* __restrict__ g1,
                                              const int* __restrict__ offsets,
                                              const int* __restrict__ csr_src,
                                              const float* __restrict__ dinv,
                                              __half* __restrict__ aggH, int N) {
    int wid = (blockIdx.x * blockDim.x + threadIdx.x) >> 6;
    if (wid >= N) return;
    int lane = threadIdx.x & 63;
    int g = lane >> 3;              // 8 edge groups
    int f8 = (lane & 7) << 3;       // 8 features per lane
    int e0 = offsets[wid], e1 = offsets[wid + 1];
    float acc[8];
#pragma unroll
    for (int i = 0; i < 8; ++i) acc[i] = 0.f;
    int ee = e0 + g;
    int s0 = (ee < e1) ? csr_src[ee] : -1;
    int s1 = (ee + 8 < e1) ? csr_src[ee + 8] : -1;
    int s2 = (ee + 16 < e1) ? csr_src[ee + 16] : -1;
    int s3 = (ee + 24 < e1) ? csr_src[ee + 24] : -1;
    for (int e = e0; e < e1; e += 32) {
        int cs0 = s0, cs1 = s1, cs2 = s2, cs3 = s3;
        int nb0 = e + 32 + g;
        s0 = (nb0 < e1) ? csr_src[nb0] : -1;    // prefetch next iter's indices
        s1 = (nb0 + 8 < e1) ? csr_src[nb0 + 8] : -1;
        s2 = (nb0 + 16 < e1) ? csr_src[nb0 + 16] : -1;
        s3 = (nb0 + 24 < e1) ? csr_src[nb0 + 24] : -1;
        bool p0 = (cs0 >= 0), p1 = (cs1 >= 0), p2 = (cs2 >= 0), p3 = (cs3 >= 0);
        int c0 = p0 ? cs0 : 0, c1 = p1 ? cs1 : 0, c2 = p2 ? cs2 : 0, c3 = p3 ? cs3 : 0;
        float4 raw0 = *reinterpret_cast<const float4*>(g1 + (size_t)c0 * HID + f8);
        float4 raw1 = *reinterpret_cast<const float4*>(g1 + (size_t)c1 * HID + f8);
        float4 raw2 = *reinterpret_cast<const float4*>(g1 + (size_t)c2 * HID + f8);
        float4 raw3 = *reinterpret_cast<const float4*>(g1 + (size_t)c3 * HID + f8);
        if (p0) {
            float2 q0 = __half22float2(*reinterpret_cast<__half2*>(&raw0.x));
            float2 q1 = __half22float2(*reinterpret_cast<__half2*>(&raw0.y));
            float2 q2 = __half22float2(*reinterpret_cast<__half2*>(&raw0.z));
            float2 q3 = __half22float2(*reinterpret_cast<__half2*>(&raw0.w));
            acc[0] += q0.x; acc[1] += q0.y; acc[2] += q1.x; acc[3] += q1.y;
            acc[4] += q2.x; acc[5] += q2.y; acc[6] += q3.x; acc[7] += q3.y;
        }
        if (p1) {
            float2 q0 = __half22float2(*reinterpret_cast<__half2*>(&raw1.x));
            float2 q1 = __half22float2(*reinterpret_cast<__half2*>(&raw1.y));
            float2 q2 = __half22float2(*reinterpret_cast<__half2*>(&raw1.z));
            float2 q3 = __half22float2(*reinterpret_cast<__half2*>(&raw1.w));
            acc[0] += q0.x; acc[1] += q0.y; acc[2] += q1.x; acc[3] += q1.y;
            acc[4] += q2.x; acc[5] += q2.y; acc[6] += q3.x; acc[7] += q3.y;
        }
        if (p2) {
            float2 q0 = __half22float2(*reinterpret_cast<__half2*>(&raw2.x));
            float2 q1 = __half22float2(*reinterpret_cast<__half2*>(&raw2.y));
            float2 q2 = __half22float2(*reinterpret_cast<__half2*>(&raw2.z));
            float2 q3 = __half22float2(*reinterpret_cast<__half2*>(&raw2.w));
            acc[0] += q0.x; acc[1] += q0.y; acc[2] += q1.x; acc[3] += q1.y;
            acc[4] += q2.x; acc[5] += q2.y; acc[6] += q3.x; acc[7] += q3.y;
        }
        if (p3) {
            float2 q0 = __half22float2(*reinterpret_cast<__half2*>(&raw3.x));
            float2 q1 = __half22float2(*reinterpret_cast<__half2*>(&raw3.y));
            float2 q2 = __half22float2(*reinterpret_cast<__half2*>(&raw3.z));
            float2 q3 = __half22float2(*reinterpret_cast<__half2*>(&raw3.w));
            acc[0] += q0.x; acc[1] += q0.y; acc[2] += q1.x; acc[3] += q1.y;
            acc[4] += q2.x; acc[5] += q2.y; acc[6] += q3.x; acc[7] += q3.y;
        }
    }
#pragma unroll
    for (int o = 8; o < 64; o <<= 1) {
#pragma unroll
        for (int i = 0; i < 8; ++i) acc[i] += __shfl_xor(acc[i], o, 64);
    }
    if (lane < 8) {
        float4 raw = *reinterpret_cast<const float4*>(g1 + (size_t)wid * HID + f8);
        float2 q0 = __half22float2(*reinterpret_cast<__half2*>(&raw.x));
        float2 q1 = __half22float2(*reinterpret_cast<__half2*>(&raw.y));
        float2 q2 = __half22float2(*reinterpret_cast<__half2*>(&raw.z));
        float2 q3 = __half22float2(*reinterpret_cast<__half2*>(&raw.w));
        float dv = dinv[wid];
        float4 st;
        *reinterpret_cast<__half2*>(&st.x) = __floats2half2_rn(dv * (acc[0] + q0.x), dv * (acc[1] + q0.y));
        *reinterpret_cast<__half2*>(&st.y) = __floats2half2_rn(dv * (acc[2] + q1.x), dv * (acc[3] + q1.y));
        *reinterpret_cast<__half2*>(&st.z) = __floats2half2_rn(dv * (acc[4] + q2.x), dv * (acc[5] + q2.y));
        *reinterpret_cast<__half2*>(&st.w) = __floats2half2_rn(dv * (acc[6] + q3.x), dv * (acc[7] + q3.y));
        *reinterpret_cast<float4*>(aggH + (size_t)wid * HID + f8) = st;
    }
}

// Fused tail: H2 = relu(aggH @ W2 + b2); out = softmax(H2 @ Wout + bout).
// aggH is fp16 (128 B rows); converted to fp32 during the LDS stage.
__global__ __launch_bounds__(256) void k_fuse(const __half* __restrict__ aggH,
                                              const float* __restrict__ W2,
                                              const float* __restrict__ b2,
                                              const float* __restrict__ Wout,
                                              const float* __restrict__ bout,
                                              float* __restrict__ out, int N) {
    __shared__ float4 sh4[64][17];      // aggH tile, padded (bank-spread)
    __shared__ float4 sW4[64 * 16];     // W2 row-major float4 quads
    __shared__ float  swout[64][NC];
    __shared__ float  sb2[64];
    __shared__ float  sbout[8];
    int tx = threadIdx.x;
    int nb0 = blockIdx.x * 64;

    const float4* W2_4 = reinterpret_cast<const float4*>(W2);
    for (int i = tx; i < 64 * 16; i += 256) sW4[i] = W2_4[i];
    const float4* aggH4 = reinterpret_cast<const float4*>(aggH);  // 8 halves per float4
    for (int i = tx; i < 64 * 8; i += 256) {
        int row = i >> 3, h8 = i & 7;
        int node = nb0 + row;
        float4 raw = {0.f, 0.f, 0.f, 0.f};
        if (node < N) raw = aggH4[(size_t)node * 8 + h8];
        float2 q0 = __half22float2(*reinterpret_cast<__half2*>(&raw.x));
        float2 q1 = __half22float2(*reinterpret_cast<__half2*>(&raw.y));
        float2 q2 = __half22float2(*reinterpret_cast<__half2*>(&raw.z));
        float2 q3 = __half22float2(*reinterpret_cast<__half2*>(&raw.w));
        sh4[row][h8 * 2]     = make_float4(q0.x, q0.y, q1.x, q1.y);
        sh4[row][h8 * 2 + 1] = make_float4(q2.x, q2.y, q3.x, q3.y);
    }
    if (tx < 64) sb2[tx] = b2[tx];
    for (int i = tx; i < 64 * NC; i += 256) swout[i / NC][i % NC] = Wout[i];
    if (tx < NC) sbout[tx] = bout[tx];
    __syncthreads();

    int ty = tx >> 4;       // local node group: rows ty*4 .. ty*4+3
    int txl = tx & 15;      // feature quad: f = txl*4 .. txl*4+3

    float acc[4][4];
#pragma unroll
    for (int j = 0; j < 4; ++j)
#pragma unroll
        for (int i = 0; i < 4; ++i) acc[j][i] = 0.f;

    for (int k4 = 0; k4 < 16; ++k4) {
        float4 w0 = sW4[(k4 * 4 + 0) * 16 + txl];
        float4 w1 = sW4[(k4 * 4 + 1) * 16 + txl];
        float4 w2 = sW4[(k4 * 4 + 2) * 16 + txl];
        float4 w3 = sW4[(k4 * 4 + 3) * 16 + txl];
#pragma unroll
        for (int j = 0; j < 4; ++j) {
            float4 hq = sh4[ty * 4 + j][k4];
            acc[j][0] = fmaf(hq.x, w0.x, fmaf(hq.y, w1.x, fmaf(hq.z, w2.x, fmaf(hq.w, w3.x, acc[j][0]))));
            acc[j][1] = fmaf(hq.x, w0.y, fmaf(hq.y, w1.y, fmaf(hq.z, w2.y, fmaf(hq.w, w3.y, acc[j][1]))));
            acc[j][2] = fmaf(hq.x, w0.z, fmaf(hq.y, w1.z, fmaf(hq.z, w2.z, fmaf(hq.w, w3.z, acc[j][2]))));
            acc[j][3] = fmaf(hq.x, w0.w, fmaf(hq.y, w1.w, fmaf(hq.z, w2.w, fmaf(hq.w, w3.w, acc[j][3]))));
        }
    }

    float pl[4][NC];
#pragma unroll
    for (int j = 0; j < 4; ++j)
#pragma unroll
        for (int c = 0; c < NC; ++c) pl[j][c] = 0.f;
#pragma unroll
    for (int j = 0; j < 4; ++j) {
#pragma unroll
        for (int i = 0; i < 4; ++i) {
            int f = txl * 4 + i;
            float h2 = fmaxf(acc[j][i] + sb2[f], 0.f);
#pragma unroll
            for (int c = 0; c < NC; ++c) pl[j][c] = fmaf(h2, swout[f][c], pl[j][c]);
        }
    }
#pragma unroll
    for (int o = 1; o < 16; o <<= 1) {
#pragma unroll
        for (int j = 0; j < 4; ++j)
#pragma unroll
            for (int c = 0; c < NC; ++c) pl[j][c] += __shfl_xor(pl[j][c], o, 64);
    }
    if (txl == 0) {
#pragma unroll
        for (int j = 0; j < 4; ++j) {
            int node = nb0 + ty * 4 + j;
            if (node < N) {
                float lg[NC];
#pragma unroll
                for (int c = 0; c < NC; ++c) lg[c] = pl[j][c] + sbout[c];
                float m = lg[0];
#pragma unroll
                for (int c = 1; c < NC; ++c) m = fmaxf(m, lg[c]);
                float ssum = 0.f, ex[NC];
#pragma unroll
                for (int c = 0; c < NC; ++c) { ex[c] = __expf(lg[c] - m); ssum += ex[c]; }
                float inv = 1.0f / ssum;
#pragma unroll
                for (int c = 0; c < NC; ++c) out[(size_t)node * NC + c] = ex[c] * inv;
            }
        }
    }
}

// ---------------- launch ----------------

extern "C" void kernel_launch(void* const* d_in, const int* in_sizes, int n_in,
                              void* d_out, int out_size, void* d_ws, size_t ws_size,
                              hipStream_t stream) {
    const float* x   = (const float*)d_in[0];
    const int*   ei  = (const int*)d_in[1];     // [2, E]: src = ei, dst = ei+E
    const float* W1  = (const float*)d_in[3];
    const float* b1  = (const float*)d_in[4];
    const float* W2  = (const float*)d_in[5];
    const float* b2  = (const float*)d_in[6];
    const float* Wo  = (const float*)d_in[7];
    const float* bo  = (const float*)d_in[8];
    float* out = (float*)d_out;

    const int N = in_sizes[2];          // batch array length = N_NODES (assumed <= 131072)
    const int E = in_sizes[1] / 2;

    // workspace partition (256B aligned)
    size_t off = 0;
    char* base = (char*)d_ws;
    auto alloc = [&](size_t bytes) -> void* {
        off = (off + 255) & ~(size_t)255;
        void* r = base + off;
        off += bytes;
        return r;
    };
    int*      cntmat  = (int*)alloc((size_t)NBLK * NBMAX * 4);
    int*      btot    = (int*)alloc((size_t)NBMAX * 4);
    int*      bbase   = (int*)alloc(((size_t)NBMAX + 1) * 4);
    unsigned* pairbuf = (unsigned*)alloc((size_t)E * 4);
    int*      offsets = (int*)alloc(((size_t)N + 1) * 4);
    int*      csr_src = (int*)alloc((size_t)E * 4);
    float*    dinv    = (float*)alloc((size_t)N * 4);
    float*    xs8     = (float*)alloc((size_t)N * 8 * 4);
    __half*   g1      = (__half*)alloc((size_t)N * HID * 2);
    __half*   aggH    = (__half*)alloc((size_t)N * HID * 2);

    const int T = 256;
    int gNF = ((N * HID) + T - 1) / T;    // one wave per node (4 waves/block)

    const int* src = ei;
    const int* dst = ei + E;

    int nb = (N + WINN - 1) >> WSH;                      // number of windows/buckets (<= 256)
    int chunk = (((E + NBLK - 1) / NBLK) + 3) & ~3;      // edges per fill block, multiple of 4

    // bucketed CSR build (+ xs8 table)
    k_bcount<<<NBLK, 512, 0, stream>>>(dst, E, chunk, nb, cntmat);
    k_wscan<<<nb, NBLK, 0, stream>>>(cntmat, nb, btot);
    k_bscan2<<<1, 256, 0, stream>>>(btot, nb, N, bbase, offsets);
    k_bfill<<<NBLK, 512, 0, stream>>>(src, dst, E, chunk, nb, bbase, cntmat, pairbuf);
    k_csr<<<nb, WINN, 0, stream>>>(pairbuf, bbase, N, x, offsets, csr_src, dinv, xs8);

    // layer 1: aggregate xs8 in input space, then @W1 per node: g1 = relu(.)*dinv (fp16)
    k_aggX<<<gNF, T, 0, stream>>>(xs8, W1, offsets, csr_src, dinv, b1, g1, N);

    // layer 2 aggregation BEFORE matmul: aggH = dinv*(g1 + Σ g1[s]) (fp16)
    k_aggG<<<gNF, T, 0, stream>>>(g1, offsets, csr_src, dinv, aggH, N);

    // fused tail: relu(aggH@W2+b2) @ Wout + bout -> softmax -> out
    int nbF = (N + 63) / 64;
    k_fuse<<<nbF, 256, 0, stream>>>(aggH, W2, b2, Wo, bo, out, N);
}